// Round 24
// baseline (127.781 us; speedup 1.0000x reference)
//
#include <hip/hip_runtime.h>
#include <math.h>

#define N_NODES 50000
#define E_EDGES 800000
#define ETOT    850000   // E + N self loops
#define F_INF   512
#define HEADS   8
#define C1      64       // HEADS*HID
#define NCLS    7
#define SLOPE   0.2f

#define BSH     9                       // bucket = dst >> 9 (512 nodes/bucket)
#define NPB     512                     // nodes per bucket
#define NB      98                      // ceil(N_NODES / NPB)
#define CAPA    10240                   // per-bucket pair capacity (E[8192]+22sigma)
#define CHUNK_A 4096
#define NBLKA   ((E_EDGES + CHUNK_A - 1) / CHUNK_A)   // 196
#define GBLK    ((N_NODES + 63) / 64)                 // 782 gemm blocks

typedef __attribute__((ext_vector_type(8))) short short8;
typedef __attribute__((ext_vector_type(4))) float f32x4;

__device__ __forceinline__ float leaky(float x){ return x > 0.f ? x : SLOPE * x; }

__device__ __forceinline__ unsigned short rne_bf16(float v){
    unsigned u = __float_as_uint(v);
    return (unsigned short)((u + 0x7fffu + ((u >> 16) & 1u)) >> 16);
}
__device__ __forceinline__ float bf_to_f(unsigned short us){
    return __uint_as_float((unsigned)us << 16);
}

// ======== W1 fragment prep + bc zeroing (fused; runs before fusedGA) =======
__global__ void k_wprep(const float* __restrict__ W1,
                        unsigned short* __restrict__ wfh,
                        int* __restrict__ bc){
    if (blockIdx.x == 0 && threadIdx.x < NB) bc[threadIdx.x] = 0;
    int t = blockIdx.x * 256 + threadIdx.x;      // 4096 threads
    int lane = t & 63, nt = (t >> 6) & 3, ks = t >> 8;
    int c  = nt * 16 + (lane & 15);
    int k0 = ks * 32 + (lane >> 4) * 8;
    size_t base = ((size_t)(ks * 4 + nt) * 64 + lane) * 8;
    #pragma unroll
    for (int j = 0; j < 8; j++)
        wfh[base + j] = rne_bf16(W1[(size_t)(k0 + j) * C1 + c]);
}

// ===== FUSED: bucketA (blocks 0..NBLKA-1) || gemm1 (blocks NBLKA..) ========
__global__ __launch_bounds__(256) void k_fusedGA(
        const int* __restrict__ ei, int* __restrict__ bc,
        unsigned long long* __restrict__ bkt,
        const float* __restrict__ x,
        const unsigned short* __restrict__ wfh,
        const float* __restrict__ a1s, const float* __restrict__ a1d,
        unsigned short* __restrict__ h1b,
        float* __restrict__ als1, float* __restrict__ ald1){
    __shared__ __align__(16) char smem[34368];
    int tid = threadIdx.x;

    if (blockIdx.x < NBLKA){
        // ---------------- bucketA body ----------------
        int* hist = (int*)smem;            // 98
        int* xofs = hist + NB;             // 99
        int* lcur = xofs + NB + 1;         // 98
        int* gb   = lcur + NB;             // 98
        unsigned long long* pairbuf = (unsigned long long*)(smem + 1600); // 32 KB
        int e0 = blockIdx.x * CHUNK_A;
        int cnt = E_EDGES - e0; if (cnt > CHUNK_A) cnt = CHUNK_A;

        for (int b = tid; b < NB; b += 256){ hist[b] = 0; lcur[b] = 0; }
        __syncthreads();

        int myS[16], myD[16];
        #pragma unroll
        for (int j = 0; j < 16; j++){
            int i = tid + j * 256;
            if (i < cnt){
                int e = e0 + i;
                myS[j] = ei[e]; myD[j] = ei[E_EDGES + e];
                atomicAdd(&hist[myD[j] >> BSH], 1);
            } else myD[j] = -1;
        }
        __syncthreads();

        if (tid < NB) xofs[tid + 1] = hist[tid];
        if (tid == 0) xofs[0] = 0;
        __syncthreads();
        for (int d = 1; d < NB; d <<= 1){
            int v = 0;
            if (tid < NB && tid + 1 > d) v = xofs[tid + 1 - d];
            __syncthreads();
            if (tid < NB) xofs[tid + 1] += v;
            __syncthreads();
        }
        if (tid < NB) gb[tid] = atomicAdd(&bc[tid], hist[tid]);

        #pragma unroll
        for (int j = 0; j < 16; j++){
            if (myD[j] >= 0){
                int b = myD[j] >> BSH;
                int p = atomicAdd(&lcur[b], 1);
                pairbuf[xofs[b] + p] =
                    ((unsigned long long)(unsigned)myD[j] << 32) | (unsigned)myS[j];
            }
        }
        __syncthreads();

        for (int i = tid; i < cnt; i += 256){
            int lo = 0, hi = NB;
            while (hi - lo > 1){
                int mid = (lo + hi) >> 1;
                if (xofs[mid] <= i) lo = mid; else hi = mid;
            }
            bkt[(size_t)lo * CAPA + gb[lo] + (i - xofs[lo])] = pairbuf[i];
        }
    } else {
        // ---------------- gemm1 body ----------------
        unsigned short* sh = (unsigned short*)smem;   // 32 KB
        int bid  = blockIdx.x - NBLKA;
        int lane = tid & 63;
        int wv   = tid >> 6;
        int row0 = bid * 64 + wv * 16;

        int arow = row0 + (lane & 15);
        if (arow >= N_NODES) arow = N_NODES - 1;
        const float* xp = x + (size_t)arow * F_INF + (lane >> 4) * 8;

        f32x4 acc[4];
        #pragma unroll
        for (int nt = 0; nt < 4; nt++) acc[nt] = (f32x4){0.f, 0.f, 0.f, 0.f};

        #pragma unroll 1
        for (int p = 0; p < 2; p++){
            const char* src = (const char*)wfh + p * 32768;
            #pragma unroll
            for (int i = 0; i < 8; i++){
                int off = i * 4096 + tid * 16;
                __builtin_amdgcn_global_load_lds(
                    (const __attribute__((address_space(1))) void*)(src + off),
                    (__attribute__((address_space(3))) void*)((char*)sh + off),
                    16, 0, 0);
            }
            float4 xv[16];
            #pragma unroll
            for (int lk = 0; lk < 8; lk++){
                xv[2 * lk]     = *(const float4*)(xp + (p * 8 + lk) * 32);
                xv[2 * lk + 1] = *(const float4*)(xp + (p * 8 + lk) * 32 + 4);
            }
            __builtin_amdgcn_sched_barrier(0);
            __syncthreads();
            #pragma unroll
            for (int lk = 0; lk < 8; lk++){
                float4 va = xv[2 * lk];
                float4 vb = xv[2 * lk + 1];
                short8 ah;
                {
                    float v_[8] = {va.x, va.y, va.z, va.w, vb.x, vb.y, vb.z, vb.w};
                    #pragma unroll
                    for (int j = 0; j < 8; j++) ah[j] = (short)rne_bf16(v_[j]);
                }
                const unsigned short* bq = sh + ((size_t)lk * 4 * 64 + lane) * 8;
                #pragma unroll
                for (int nt = 0; nt < 4; nt++){
                    short8 bh = *(const short8*)(bq + nt * 512);
                    acc[nt] = __builtin_amdgcn_mfma_f32_16x16x32_bf16(ah, bh, acc[nt], 0, 0, 0);
                }
            }
            __syncthreads();
        }

        int g = lane >> 4, c = lane & 15;
        #pragma unroll
        for (int nt = 0; nt < 4; nt++){
            #pragma unroll
            for (int r = 0; r < 4; r++){
                int row = row0 + g * 4 + r;
                if (row < N_NODES)
                    h1b[(size_t)row * C1 + nt * 16 + c] = rne_bf16(acc[nt][r]);
            }
        }

        float s_[4][4], d_[4][4];
        #pragma unroll
        for (int nt = 0; nt < 4; nt++){
            float as = a1s[nt * 16 + c], ad = a1d[nt * 16 + c];
            #pragma unroll
            for (int r = 0; r < 4; r++){
                float vs = acc[nt][r] * as;
                float vd = acc[nt][r] * ad;
                vs += __shfl_xor(vs, 1); vs += __shfl_xor(vs, 2); vs += __shfl_xor(vs, 4);
                vd += __shfl_xor(vd, 1); vd += __shfl_xor(vd, 2); vd += __shfl_xor(vd, 4);
                s_[nt][r] = vs; d_[nt][r] = vd;
            }
        }
        if ((lane & 7) == 0){
            int b = c >> 3;
            #pragma unroll
            for (int nt = 0; nt < 4; nt++){
                int h = nt * 2 + b;
                #pragma unroll
                for (int r = 0; r < 4; r++){
                    int row = row0 + g * 4 + r;
                    if (row < N_NODES){
                        als1[row * HEADS + h] = s_[nt][r];
                        ald1[row * HEADS + h] = d_[nt][r];
                    }
                }
            }
        }
    }
}

// pass B: per-bucket CSR built in LDS, coalesced global writes.
__global__ __launch_bounds__(256) void k_bucketB(
        const unsigned long long* __restrict__ bkt, const int* __restrict__ bc,
        int* __restrict__ ofs, int* __restrict__ deg, int* __restrict__ csr_src){
    __shared__ int hist[NPB], xofs[NPB + 1], lcur[NPB], sp[256], bcs[128];
    __shared__ int csr[CAPA + NPB];    // 43 KB
    int tid = threadIdx.x;
    int b = blockIdx.x;
    int d0 = b << BSH;
    int nn = N_NODES - d0; if (nn > NPB) nn = NPB;
    int cnt = bc[b];

    {
        int v2 = 0;
        if (tid < NB){
            int d0b = tid << BSH;
            int nnb = N_NODES - d0b; if (nnb > NPB) nnb = NPB;
            v2 = bc[tid] + nnb;
        }
        if (tid < 128) bcs[tid] = v2;
        __syncthreads();
        for (int d = 1; d < 128; d <<= 1){
            int u = 0;
            if (tid < 128 && tid >= d) u = bcs[tid - d];
            __syncthreads();
            if (tid < 128) bcs[tid] += u;
            __syncthreads();
        }
    }
    int gbase = (b > 0) ? bcs[b - 1] : 0;

    for (int i = tid; i < NPB; i += 256){ hist[i] = 0; lcur[i] = 0; }
    __syncthreads();
    for (int i = tid; i < cnt; i += 256){
        int d = (int)(bkt[(size_t)b * CAPA + i] >> 32);
        atomicAdd(&hist[d - d0], 1);
    }
    __syncthreads();

    int a0 = (2 * tid     < nn) ? hist[2 * tid]     + 1 : 0;
    int a1 = (2 * tid + 1 < nn) ? hist[2 * tid + 1] + 1 : 0;
    sp[tid] = a0 + a1;
    __syncthreads();
    for (int d = 1; d < 256; d <<= 1){
        int u = (tid >= d) ? sp[tid - d] : 0;
        __syncthreads();
        sp[tid] += u;
        __syncthreads();
    }
    int base = sp[tid] - (a0 + a1);
    xofs[2 * tid]     = base;
    xofs[2 * tid + 1] = base + a0;
    if (tid == 255) xofs[NPB] = sp[255];
    __syncthreads();

    for (int i = tid; i < cnt; i += 256){
        unsigned long long pr = bkt[(size_t)b * CAPA + i];
        int d = (int)(pr >> 32) - d0;
        int s = (int)(pr & 0xffffffffu);
        int p = atomicAdd(&lcur[d], 1);
        csr[xofs[d] + p] = s;
    }
    __syncthreads();

    for (int t = tid; t < nn; t += 256){
        int ine = hist[t];
        csr[xofs[t] + ine] = d0 + t;          // self-loop in last slot
        ofs[d0 + t] = gbase + xofs[t];
        deg[d0 + t] = ine + 1;
    }
    __syncthreads();

    int total = xofs[NPB];                    // == cnt + nn
    for (int i = tid; i < total; i += 256)
        csr_src[gbase + i] = csr[i];
}

// ================= layer1 aggregate + normalize + ELU + layer2 GEMM ========
// one wave per node; lane = feature; 32-deep batch of the proven R13/R21
// form (direct clamped loads, independent addresses). >99.9% of nodes now
// complete in ONE batch iteration.
__global__ __launch_bounds__(256) void k_agg1(
        const int* __restrict__ csr_src, const int* __restrict__ ofs,
        const int* __restrict__ deg,
        const float* __restrict__ als1, const float* __restrict__ ald1,
        const unsigned short* __restrict__ h1b,
        const float* __restrict__ b1, const float* __restrict__ W2,
        const float* __restrict__ a2s, const float* __restrict__ a2d,
        float* __restrict__ h2p, float* __restrict__ ald2){
    int lane = threadIdx.x & 63;
    int wv   = threadIdx.x >> 6;
    int n = blockIdx.x * 4 + wv;
    int h = lane >> 3;            // head (feature duty AND exp duty)
    int jm = lane & 7;            // exp duty: edge sub-index
    int start = __builtin_amdgcn_readfirstlane(ofs[n]);
    int dcount = __builtin_amdgcn_readfirstlane(deg[n]);
    int end = start + dcount;
    float aldv = ald1[n * HEADS + h];
    float acc = 0.f, dsum = 0.f;
    int base = lane & 56;
    for (int i = start; i < end; i += 32){
        int sv[32];
        #pragma unroll
        for (int j = 0; j < 32; j++){
            int id = i + j;
            sv[j] = csr_src[id < end ? id : end - 1];
        }
        // exp duty (per-lane loads, clamped addresses valid)
        float er[4];
        #pragma unroll
        for (int r = 0; r < 4; r++){
            int idr = i + r * 8 + jm;
            int smr = csr_src[idr < end ? idr : end - 1];
            er[r] = (idr < end) ? __expf(leaky(als1[smr * HEADS + h] + aldv)) : 0.f;
        }
        // issue all 32 feature gathers
        float hv[32];
        #pragma unroll
        for (int j = 0; j < 32; j++)
            hv[j] = bf_to_f(h1b[(size_t)sv[j] * C1 + lane]);
        #pragma unroll
        for (int r = 0; r < 4; r++){
            #pragma unroll
            for (int j = 0; j < 8; j++){
                float ex = __shfl(er[r], base | j);
                acc = fmaf(ex, hv[r * 8 + j], acc);
                dsum += ex;
            }
        }
    }
    float v = acc / (dsum + 1e-16f) + b1[lane];
    float el = v > 0.f ? v : expm1f(v);
    float p[NCLS];
    #pragma unroll
    for (int c = 0; c < NCLS; c++) p[c] = el * W2[lane * NCLS + c];
    #pragma unroll
    for (int o = 1; o < 64; o <<= 1){
        #pragma unroll
        for (int c = 0; c < NCLS; c++) p[c] += __shfl_xor(p[c], o);
    }
    if (lane == 0){
        float ps = 0.f, pd = 0.f;
        #pragma unroll
        for (int c = 0; c < NCLS; c++){
            h2p[n * 8 + c] = p[c];
            ps = fmaf(p[c], a2s[c], ps);
            pd = fmaf(p[c], a2d[c], pd);
        }
        h2p[n * 8 + 7] = ps;        // als2 packed into slot 7
        ald2[n] = pd;
    }
}

// ================= layer2 aggregate + log_softmax (packed gather) ==========
// h2p[s*8+c]: c<7 -> feature, c==7 -> als2. One 32B gather per edge serves
// both; als2 broadcast to the group via shfl from lane c==7.
__global__ __launch_bounds__(256) void k_agg2(
        const int* __restrict__ csr_src, const int* __restrict__ ofs,
        const int* __restrict__ deg,
        const float* __restrict__ h2p, const float* __restrict__ ald2,
        const float* __restrict__ b2, float* __restrict__ out){
    int lane = threadIdx.x & 63;
    int wv   = threadIdx.x >> 6;
    int n = blockIdx.x * 4 + wv;
    int c = lane & 7, g = lane >> 3;
    int start = __builtin_amdgcn_readfirstlane(ofs[n]);
    int dcount = __builtin_amdgcn_readfirstlane(deg[n]);
    float aldv = ald2[n];
    float acc = 0.f;
    int grp = lane & 56;
    for (int i = g; i < dcount; i += 16){
        int ia = start + i;
        bool ok1 = (i + 8) < dcount;
        int ib = ok1 ? ia + 8 : ia;
        int s0 = csr_src[ia];
        int s1 = csr_src[ib];
        float q0 = h2p[s0 * 8 + c];
        float q1 = h2p[s1 * 8 + c];
        float al0 = __shfl(q0, grp | 7);
        float al1 = __shfl(q1, grp | 7);
        float hv0 = (c < NCLS) ? q0 : 1.f;
        float hv1 = (c < NCLS) ? q1 : 1.f;
        float ex0 = __expf(leaky(al0 + aldv));
        float ex1 = ok1 ? __expf(leaky(al1 + aldv)) : 0.f;
        acc = fmaf(ex0, hv0, acc);
        acc = fmaf(ex1, hv1, acc);
    }
    acc += __shfl_xor(acc, 8); acc += __shfl_xor(acc, 16); acc += __shfl_xor(acc, 32);
    float den = __shfl(acc, lane | 7) + 1e-16f;
    float v = acc / den + b2[c < NCLS ? c : 0];
    float vm = (c < NCLS) ? v : -INFINITY;
    vm = fmaxf(vm, __shfl_xor(vm, 1));
    vm = fmaxf(vm, __shfl_xor(vm, 2));
    vm = fmaxf(vm, __shfl_xor(vm, 4));
    float ev = (c < NCLS) ? __expf(v - vm) : 0.f;
    ev += __shfl_xor(ev, 1); ev += __shfl_xor(ev, 2); ev += __shfl_xor(ev, 4);
    float lse = vm + logf(ev);
    if (g == 0 && c < NCLS) out[n * NCLS + c] = v - lse;
}

extern "C" void kernel_launch(void* const* d_in, const int* in_sizes, int n_in,
                              void* d_out, int out_size, void* d_ws, size_t ws_size,
                              hipStream_t stream){
    const float* x    = (const float*)d_in[0];
    const int*   ei   = (const int*)  d_in[1];
    const float* W1   = (const float*)d_in[2];
    const float* a1s  = (const float*)d_in[3];
    const float* a1d  = (const float*)d_in[4];
    const float* b1   = (const float*)d_in[5];
    const float* W2   = (const float*)d_in[6];
    const float* a2s  = (const float*)d_in[7];
    const float* a2d  = (const float*)d_in[8];
    const float* b2   = (const float*)d_in[9];
    float* out = (float*)d_out;

    float* w = (float*)d_ws;
    unsigned short* h1b = (unsigned short*)w;  w += (size_t)N_NODES * C1 / 2;
    float*    als1 = w;              w += N_NODES * HEADS;
    float*    ald1 = w;              w += N_NODES * HEADS;
    float*    h2p  = w;              w += N_NODES * 8;
    float*    ald2 = w;              w += N_NODES;
    unsigned short* wfh = (unsigned short*)w;  w += (16 * 4 * 64 * 8) / 2;
    int* deg    = (int*)w;           w += N_NODES;
    int* ofs    = (int*)w;           w += N_NODES;
    int* bc     = (int*)w;           w += 128;
    unsigned long long* bkt = (unsigned long long*)w;  w += (size_t)NB * CAPA * 2;
    int* csr_src = (int*)w;          w += ETOT;

    k_wprep  <<<16, 256, 0, stream>>>(W1, wfh, bc);
    k_fusedGA<<<NBLKA + GBLK, 256, 0, stream>>>(ei, bc, bkt, x, wfh, a1s, a1d,
                                                h1b, als1, ald1);
    k_bucketB<<<NB, 256, 0, stream>>>(bkt, bc, ofs, deg, csr_src);
    k_agg1   <<<N_NODES / 4, 256, 0, stream>>>(csr_src, ofs, deg, als1, ald1, h1b,
                                               b1, W2, a2s, a2d, h2p, ald2);
    k_agg2   <<<N_NODES / 4, 256, 0, stream>>>(csr_src, ofs, deg, h2p, ald2, b2, out);
}

// Round 27
// 119.939 us; speedup vs baseline: 1.0654x; 1.0654x over previous
//
#include <hip/hip_runtime.h>
#include <math.h>

#define N_NODES 50000
#define E_EDGES 800000
#define ETOT    850000   // E + N self loops
#define F_INF   512
#define HEADS   8
#define C1      64       // HEADS*HID
#define NCLS    7
#define SLOPE   0.2f

#define BSH     9                       // bucket = dst >> 9 (512 nodes/bucket)
#define NPB     512                     // nodes per bucket
#define NB      98                      // ceil(N_NODES / NPB)
#define CAPA    10240                   // per-bucket pair capacity (E[8192]+22sigma)
#define CHUNK_A 4096
#define NBLKA   ((E_EDGES + CHUNK_A - 1) / CHUNK_A)   // 196
#define GBLK    ((N_NODES + 63) / 64)                 // 782 gemm blocks

typedef __attribute__((ext_vector_type(8))) short short8;
typedef __attribute__((ext_vector_type(4))) float f32x4;

__device__ __forceinline__ float leaky(float x){ return x > 0.f ? x : SLOPE * x; }

__device__ __forceinline__ unsigned short rne_bf16(float v){
    unsigned u = __float_as_uint(v);
    return (unsigned short)((u + 0x7fffu + ((u >> 16) & 1u)) >> 16);
}
__device__ __forceinline__ float bf_to_f(unsigned short us){
    return __uint_as_float((unsigned)us << 16);
}

// ======== W1 fragment prep + bc zeroing (fused; runs before fusedGA) =======
__global__ void k_wprep(const float* __restrict__ W1,
                        unsigned short* __restrict__ wfh,
                        int* __restrict__ bc){
    if (blockIdx.x == 0 && threadIdx.x < NB) bc[threadIdx.x] = 0;
    int t = blockIdx.x * 256 + threadIdx.x;      // 4096 threads
    int lane = t & 63, nt = (t >> 6) & 3, ks = t >> 8;
    int c  = nt * 16 + (lane & 15);
    int k0 = ks * 32 + (lane >> 4) * 8;
    size_t base = ((size_t)(ks * 4 + nt) * 64 + lane) * 8;
    #pragma unroll
    for (int j = 0; j < 8; j++)
        wfh[base + j] = rne_bf16(W1[(size_t)(k0 + j) * C1 + c]);
}

// ===== FUSED: bucketA (blocks 0..NBLKA-1) || gemm1 (blocks NBLKA..) ========
__global__ __launch_bounds__(256) void k_fusedGA(
        const int* __restrict__ ei, int* __restrict__ bc,
        unsigned long long* __restrict__ bkt,
        const float* __restrict__ x,
        const unsigned short* __restrict__ wfh,
        const float* __restrict__ a1s, const float* __restrict__ a1d,
        unsigned short* __restrict__ h1b,
        float* __restrict__ als1, float* __restrict__ ald1){
    __shared__ __align__(16) char smem[34368];
    int tid = threadIdx.x;

    if (blockIdx.x < NBLKA){
        // ---------------- bucketA body ----------------
        int* hist = (int*)smem;            // 98
        int* xofs = hist + NB;             // 99
        int* lcur = xofs + NB + 1;         // 98
        int* gb   = lcur + NB;             // 98
        unsigned long long* pairbuf = (unsigned long long*)(smem + 1600); // 32 KB
        int e0 = blockIdx.x * CHUNK_A;
        int cnt = E_EDGES - e0; if (cnt > CHUNK_A) cnt = CHUNK_A;

        for (int b = tid; b < NB; b += 256){ hist[b] = 0; lcur[b] = 0; }
        __syncthreads();

        int myS[16], myD[16];
        #pragma unroll
        for (int j = 0; j < 16; j++){
            int i = tid + j * 256;
            if (i < cnt){
                int e = e0 + i;
                myS[j] = ei[e]; myD[j] = ei[E_EDGES + e];
                atomicAdd(&hist[myD[j] >> BSH], 1);
            } else myD[j] = -1;
        }
        __syncthreads();

        if (tid < NB) xofs[tid + 1] = hist[tid];
        if (tid == 0) xofs[0] = 0;
        __syncthreads();
        for (int d = 1; d < NB; d <<= 1){
            int v = 0;
            if (tid < NB && tid + 1 > d) v = xofs[tid + 1 - d];
            __syncthreads();
            if (tid < NB) xofs[tid + 1] += v;
            __syncthreads();
        }
        if (tid < NB) gb[tid] = atomicAdd(&bc[tid], hist[tid]);

        #pragma unroll
        for (int j = 0; j < 16; j++){
            if (myD[j] >= 0){
                int b = myD[j] >> BSH;
                int p = atomicAdd(&lcur[b], 1);
                pairbuf[xofs[b] + p] =
                    ((unsigned long long)(unsigned)myD[j] << 32) | (unsigned)myS[j];
            }
        }
        __syncthreads();

        for (int i = tid; i < cnt; i += 256){
            int lo = 0, hi = NB;
            while (hi - lo > 1){
                int mid = (lo + hi) >> 1;
                if (xofs[mid] <= i) lo = mid; else hi = mid;
            }
            bkt[(size_t)lo * CAPA + gb[lo] + (i - xofs[lo])] = pairbuf[i];
        }
    } else {
        // ---------------- gemm1 body ----------------
        unsigned short* sh = (unsigned short*)smem;   // 32 KB
        int bid  = blockIdx.x - NBLKA;
        int lane = tid & 63;
        int wv   = tid >> 6;
        int row0 = bid * 64 + wv * 16;

        int arow = row0 + (lane & 15);
        if (arow >= N_NODES) arow = N_NODES - 1;
        const float* xp = x + (size_t)arow * F_INF + (lane >> 4) * 8;

        f32x4 acc[4];
        #pragma unroll
        for (int nt = 0; nt < 4; nt++) acc[nt] = (f32x4){0.f, 0.f, 0.f, 0.f};

        #pragma unroll 1
        for (int p = 0; p < 2; p++){
            const char* src = (const char*)wfh + p * 32768;
            #pragma unroll
            for (int i = 0; i < 8; i++){
                int off = i * 4096 + tid * 16;
                __builtin_amdgcn_global_load_lds(
                    (const __attribute__((address_space(1))) void*)(src + off),
                    (__attribute__((address_space(3))) void*)((char*)sh + off),
                    16, 0, 0);
            }
            float4 xv[16];
            #pragma unroll
            for (int lk = 0; lk < 8; lk++){
                xv[2 * lk]     = *(const float4*)(xp + (p * 8 + lk) * 32);
                xv[2 * lk + 1] = *(const float4*)(xp + (p * 8 + lk) * 32 + 4);
            }
            __builtin_amdgcn_sched_barrier(0);
            __syncthreads();
            #pragma unroll
            for (int lk = 0; lk < 8; lk++){
                float4 va = xv[2 * lk];
                float4 vb = xv[2 * lk + 1];
                short8 ah;
                {
                    float v_[8] = {va.x, va.y, va.z, va.w, vb.x, vb.y, vb.z, vb.w};
                    #pragma unroll
                    for (int j = 0; j < 8; j++) ah[j] = (short)rne_bf16(v_[j]);
                }
                const unsigned short* bq = sh + ((size_t)lk * 4 * 64 + lane) * 8;
                #pragma unroll
                for (int nt = 0; nt < 4; nt++){
                    short8 bh = *(const short8*)(bq + nt * 512);
                    acc[nt] = __builtin_amdgcn_mfma_f32_16x16x32_bf16(ah, bh, acc[nt], 0, 0, 0);
                }
            }
            __syncthreads();
        }

        int g = lane >> 4, c = lane & 15;
        #pragma unroll
        for (int nt = 0; nt < 4; nt++){
            #pragma unroll
            for (int r = 0; r < 4; r++){
                int row = row0 + g * 4 + r;
                if (row < N_NODES)
                    h1b[(size_t)row * C1 + nt * 16 + c] = rne_bf16(acc[nt][r]);
            }
        }

        float s_[4][4], d_[4][4];
        #pragma unroll
        for (int nt = 0; nt < 4; nt++){
            float as = a1s[nt * 16 + c], ad = a1d[nt * 16 + c];
            #pragma unroll
            for (int r = 0; r < 4; r++){
                float vs = acc[nt][r] * as;
                float vd = acc[nt][r] * ad;
                vs += __shfl_xor(vs, 1); vs += __shfl_xor(vs, 2); vs += __shfl_xor(vs, 4);
                vd += __shfl_xor(vd, 1); vd += __shfl_xor(vd, 2); vd += __shfl_xor(vd, 4);
                s_[nt][r] = vs; d_[nt][r] = vd;
            }
        }
        if ((lane & 7) == 0){
            int b = c >> 3;
            #pragma unroll
            for (int nt = 0; nt < 4; nt++){
                int h = nt * 2 + b;
                #pragma unroll
                for (int r = 0; r < 4; r++){
                    int row = row0 + g * 4 + r;
                    if (row < N_NODES){
                        als1[row * HEADS + h] = s_[nt][r];
                        ald1[row * HEADS + h] = d_[nt][r];
                    }
                }
            }
        }
    }
}

// pass B: per-bucket CSR built in LDS, coalesced global writes.
__global__ __launch_bounds__(256) void k_bucketB(
        const unsigned long long* __restrict__ bkt, const int* __restrict__ bc,
        int* __restrict__ ofs, int* __restrict__ deg, int* __restrict__ csr_src){
    __shared__ int hist[NPB], xofs[NPB + 1], lcur[NPB], sp[256], bcs[128];
    __shared__ int csr[CAPA + NPB];    // 43 KB
    int tid = threadIdx.x;
    int b = blockIdx.x;
    int d0 = b << BSH;
    int nn = N_NODES - d0; if (nn > NPB) nn = NPB;
    int cnt = bc[b];

    {
        int v2 = 0;
        if (tid < NB){
            int d0b = tid << BSH;
            int nnb = N_NODES - d0b; if (nnb > NPB) nnb = NPB;
            v2 = bc[tid] + nnb;
        }
        if (tid < 128) bcs[tid] = v2;
        __syncthreads();
        for (int d = 1; d < 128; d <<= 1){
            int u = 0;
            if (tid < 128 && tid >= d) u = bcs[tid - d];
            __syncthreads();
            if (tid < 128) bcs[tid] += u;
            __syncthreads();
        }
    }
    int gbase = (b > 0) ? bcs[b - 1] : 0;

    for (int i = tid; i < NPB; i += 256){ hist[i] = 0; lcur[i] = 0; }
    __syncthreads();
    for (int i = tid; i < cnt; i += 256){
        int d = (int)(bkt[(size_t)b * CAPA + i] >> 32);
        atomicAdd(&hist[d - d0], 1);
    }
    __syncthreads();

    int a0 = (2 * tid     < nn) ? hist[2 * tid]     + 1 : 0;
    int a1 = (2 * tid + 1 < nn) ? hist[2 * tid + 1] + 1 : 0;
    sp[tid] = a0 + a1;
    __syncthreads();
    for (int d = 1; d < 256; d <<= 1){
        int u = (tid >= d) ? sp[tid - d] : 0;
        __syncthreads();
        sp[tid] += u;
        __syncthreads();
    }
    int base = sp[tid] - (a0 + a1);
    xofs[2 * tid]     = base;
    xofs[2 * tid + 1] = base + a0;
    if (tid == 255) xofs[NPB] = sp[255];
    __syncthreads();

    for (int i = tid; i < cnt; i += 256){
        unsigned long long pr = bkt[(size_t)b * CAPA + i];
        int d = (int)(pr >> 32) - d0;
        int s = (int)(pr & 0xffffffffu);
        int p = atomicAdd(&lcur[d], 1);
        csr[xofs[d] + p] = s;
    }
    __syncthreads();

    for (int t = tid; t < nn; t += 256){
        int ine = hist[t];
        csr[xofs[t] + ine] = d0 + t;          // self-loop in last slot
        ofs[d0 + t] = gbase + xofs[t];
        deg[d0 + t] = ine + 1;
    }
    __syncthreads();

    int total = xofs[NPB];                    // == cnt + nn
    for (int i = tid; i < total; i += 256)
        csr_src[gbase + i] = csr[i];
}

// ================= layer1 aggregate + normalize + ELU + layer2 GEMM ========
// one wave per node; lane = feature; plain 16-edge batch, direct clamped
// loads (R13/R16/R21 form — independent addresses, max MLP).
__global__ __launch_bounds__(256) void k_agg1(
        const int* __restrict__ csr_src, const int* __restrict__ ofs,
        const int* __restrict__ deg,
        const float* __restrict__ als1, const float* __restrict__ ald1,
        const unsigned short* __restrict__ h1b,
        const float* __restrict__ b1, const float* __restrict__ W2,
        const float* __restrict__ a2s, const float* __restrict__ a2d,
        float* __restrict__ h2, float* __restrict__ als2, float* __restrict__ ald2){
    int lane = threadIdx.x & 63;
    int wv   = threadIdx.x >> 6;
    int n = blockIdx.x * 4 + wv;
    int h = lane >> 3;            // head (feature duty AND exp duty)
    int jm = lane & 7;            // exp duty: edge sub-index
    int start = __builtin_amdgcn_readfirstlane(ofs[n]);
    int dcount = __builtin_amdgcn_readfirstlane(deg[n]);
    int end = start + dcount;
    float aldv = ald1[n * HEADS + h];
    float acc = 0.f, dsum = 0.f;
    for (int i = start; i < end; i += 16){
        int sv[16];
        #pragma unroll
        for (int j = 0; j < 16; j++){
            int id = i + j;
            sv[j] = csr_src[id < end ? id : end - 1];
        }
        // exp duty (per-lane loads, clamped addresses valid)
        int id0 = i + jm, id1 = i + 8 + jm;
        int sm0 = csr_src[id0 < end ? id0 : end - 1];
        int sm1 = csr_src[id1 < end ? id1 : end - 1];
        float e0 = (id0 < end) ? __expf(leaky(als1[sm0 * HEADS + h] + aldv)) : 0.f;
        float e1 = (id1 < end) ? __expf(leaky(als1[sm1 * HEADS + h] + aldv)) : 0.f;
        // issue all 16 feature gathers
        float hv[16];
        #pragma unroll
        for (int j = 0; j < 16; j++)
            hv[j] = bf_to_f(h1b[(size_t)sv[j] * C1 + lane]);
        int base = lane & 56;
        #pragma unroll
        for (int j = 0; j < 8; j++){
            float ex = __shfl(e0, base | j);
            acc = fmaf(ex, hv[j], acc);
            dsum += ex;
        }
        #pragma unroll
        for (int j = 0; j < 8; j++){
            float ex = __shfl(e1, base | j);
            acc = fmaf(ex, hv[8 + j], acc);
            dsum += ex;
        }
    }
    float v = acc / (dsum + 1e-16f) + b1[lane];
    float el = v > 0.f ? v : expm1f(v);
    float p[NCLS];
    #pragma unroll
    for (int c = 0; c < NCLS; c++) p[c] = el * W2[lane * NCLS + c];
    #pragma unroll
    for (int o = 1; o < 64; o <<= 1){
        #pragma unroll
        for (int c = 0; c < NCLS; c++) p[c] += __shfl_xor(p[c], o);
    }
    if (lane == 0){
        float ps = 0.f, pd = 0.f;
        #pragma unroll
        for (int c = 0; c < NCLS; c++){
            h2[n * NCLS + c] = p[c];
            ps = fmaf(p[c], a2s[c], ps);
            pd = fmaf(p[c], a2d[c], pd);
        }
        als2[n] = ps; ald2[n] = pd;
    }
}

// ================= layer2 aggregate + log_softmax (lean) ===================
__global__ __launch_bounds__(256) void k_agg2(
        const int* __restrict__ csr_src, const int* __restrict__ ofs,
        const int* __restrict__ deg,
        const float* __restrict__ als2, const float* __restrict__ ald2,
        const float* __restrict__ h2, const float* __restrict__ b2,
        float* __restrict__ out){
    int lane = threadIdx.x & 63;
    int wv   = threadIdx.x >> 6;
    int n = blockIdx.x * 4 + wv;
    int c = lane & 7, g = lane >> 3;
    int start = __builtin_amdgcn_readfirstlane(ofs[n]);
    int dcount = __builtin_amdgcn_readfirstlane(deg[n]);
    float aldv = ald2[n];
    float acc = 0.f;
    for (int i = g; i < dcount; i += 16){
        int ia = start + i;
        bool ok1 = (i + 8) < dcount;
        int ib = ok1 ? ia + 8 : ia;
        int s0 = csr_src[ia];
        int s1 = csr_src[ib];
        float al0 = als2[s0], al1 = als2[s1];
        float hv0 = (c < NCLS) ? h2[s0 * NCLS + c] : 1.f;
        float hv1 = (c < NCLS) ? h2[s1 * NCLS + c] : 1.f;
        float ex0 = __expf(leaky(al0 + aldv));
        float ex1 = ok1 ? __expf(leaky(al1 + aldv)) : 0.f;
        acc = fmaf(ex0, hv0, acc);
        acc = fmaf(ex1, hv1, acc);
    }
    acc += __shfl_xor(acc, 8); acc += __shfl_xor(acc, 16); acc += __shfl_xor(acc, 32);
    float den = __shfl(acc, lane | 7) + 1e-16f;
    float v = acc / den + b2[c < NCLS ? c : 0];
    float vm = (c < NCLS) ? v : -INFINITY;
    vm = fmaxf(vm, __shfl_xor(vm, 1));
    vm = fmaxf(vm, __shfl_xor(vm, 2));
    vm = fmaxf(vm, __shfl_xor(vm, 4));
    float ev = (c < NCLS) ? __expf(v - vm) : 0.f;
    ev += __shfl_xor(ev, 1); ev += __shfl_xor(ev, 2); ev += __shfl_xor(ev, 4);
    float lse = vm + logf(ev);
    if (g == 0 && c < NCLS) out[n * NCLS + c] = v - lse;
}

extern "C" void kernel_launch(void* const* d_in, const int* in_sizes, int n_in,
                              void* d_out, int out_size, void* d_ws, size_t ws_size,
                              hipStream_t stream){
    const float* x    = (const float*)d_in[0];
    const int*   ei   = (const int*)  d_in[1];
    const float* W1   = (const float*)d_in[2];
    const float* a1s  = (const float*)d_in[3];
    const float* a1d  = (const float*)d_in[4];
    const float* b1   = (const float*)d_in[5];
    const float* W2   = (const float*)d_in[6];
    const float* a2s  = (const float*)d_in[7];
    const float* a2d  = (const float*)d_in[8];
    const float* b2   = (const float*)d_in[9];
    float* out = (float*)d_out;

    float* w = (float*)d_ws;
    unsigned short* h1b = (unsigned short*)w;  w += (size_t)N_NODES * C1 / 2;
    float*    als1 = w;              w += N_NODES * HEADS;
    float*    ald1 = w;              w += N_NODES * HEADS;
    float*    h2   = w;              w += N_NODES * NCLS;
    float*    als2 = w;              w += N_NODES;
    float*    ald2 = w;              w += N_NODES;
    unsigned short* wfh = (unsigned short*)w;  w += (16 * 4 * 64 * 8) / 2;
    int* deg    = (int*)w;           w += N_NODES;
    int* ofs    = (int*)w;           w += N_NODES;
    int* bc     = (int*)w;           w += 128;
    unsigned long long* bkt = (unsigned long long*)w;  w += (size_t)NB * CAPA * 2;
    int* csr_src = (int*)w;          w += ETOT;

    k_wprep  <<<16, 256, 0, stream>>>(W1, wfh, bc);
    k_fusedGA<<<NBLKA + GBLK, 256, 0, stream>>>(ei, bc, bkt, x, wfh, a1s, a1d,
                                                h1b, als1, ald1);
    k_bucketB<<<NB, 256, 0, stream>>>(bkt, bc, ofs, deg, csr_src);
    k_agg1   <<<N_NODES / 4, 256, 0, stream>>>(csr_src, ofs, deg, als1, ald1, h1b,
                                               b1, W2, a2s, a2d, h2, als2, ald2);
    k_agg2   <<<N_NODES / 4, 256, 0, stream>>>(csr_src, ofs, deg, als2, ald2, h2, b2, out);
}